// Round 13
// baseline (109.409 us; speedup 1.0000x reference)
//
#include <hip/hip_runtime.h>

namespace {

constexpr int NS = 256;      // samples
constexpr int MP = 128;      // patches
constexpr int TSTEPS = 200;  // timesteps
constexpr int BLK = 1024;    // 16 waves -> 4 waves/SIMD (max interleave)

__device__ __forceinline__ float4 ldg4(const float* p) {
  return *reinterpret_cast<const float4*>(p);
}
__device__ __forceinline__ float clamp01(float v) {
  return fminf(fmaxf(v, 0.0f), 1.0f);
}
// LDS-visibility barrier that does NOT drain vmcnt (stores stay in flight).
__device__ __forceinline__ void step_barrier() {
  asm volatile("s_waitcnt lgkmcnt(0)" ::: "memory");
  __builtin_amdgcn_s_barrier();
  asm volatile("" ::: "memory");
}
// f32 += dot(f16x2, f16x2) — single VOP3P instruction (R11/R12-verified)
__device__ __forceinline__ float dot2(unsigned a, unsigned b, float c) {
  float d;
  asm("v_dot2_f32_f16 %0, %1, %2, %3" : "=v"(d) : "v"(a), "v"(b), "v"(c));
  return d;
}
// pack two f32 -> f16x2 (RTZ)
__device__ __forceinline__ unsigned pkrtz(float a, float b) {
  typedef __fp16 h2v __attribute__((ext_vector_type(2)));
  h2v r = __builtin_amdgcn_cvt_pkrtz(a, b);
  return __builtin_bit_cast(unsigned, r);
}
// rotate-add within 16-lane DPP row (R6-proven): 0x121/0x122/0x124/0x128
template <int CTRL>
__device__ __forceinline__ float dpp_radd(float x) {
  int yi = __builtin_amdgcn_update_dpp(0, __float_as_int(x), CTRL, 0xF, 0xF, true);
  return x + __int_as_float(yi);
}
// Swizzled uint4 (b128 = 8 f16) index into f16 Q: 16 quads/row, XOR row-octet
__device__ __forceinline__ int qidx16(int row, int ch) {
  return (row << 4) + (ch ^ ((row >> 3) & 7));
}

__global__ __launch_bounds__(BLK, 1)
void sir_meta_kernel(const float* __restrict__ Rg,
                     const float* __restrict__ Tg,
                     const float* __restrict__ rho0g,
                     const float* __restrict__ betag,
                     float* __restrict__ outg)
{
  __shared__ __align__(16) float rs[MP];          // 1/rowsum (f32 exact)
  __shared__ __align__(16) float sbin[MP];        // sqrt(beta/neff) (f32 exact)
  __shared__ __align__(16) float scr[BLK];
  __shared__ __align__(16) unsigned xh[2][64];    // x as f16 pairs, dbuffered
  __shared__ __align__(16) uint4 q16[MP * 16];    // Q in f16 pairs (32KB)
  __shared__ __align__(16) uint4 gh[MP * 16];     // G in f16 pairs (8KB)

  const int tid = threadIdx.x;
  const int n = blockIdx.x;
  const float* __restrict__ Rn = Rg + (size_t)n * MP * MP;

  // ---- S1: row sums -> rs = 1/rowsum (16 waves x 8 rows) ----
  {
    const int wave = tid >> 6;
    const int lane = tid & 63;
    const int half = lane >> 5;
    const int l32 = lane & 31;
    for (int it = 0; it < 4; ++it) {
      const int row = wave * 8 + it * 2 + half;
      float4 v = ldg4(Rn + row * MP + l32 * 4);
      float s = (v.x + v.y) + (v.z + v.w);
      s += __shfl_xor(s, 1);
      s += __shfl_xor(s, 2);
      s += __shfl_xor(s, 4);
      s += __shfl_xor(s, 8);
      s += __shfl_xor(s, 16);
      if (l32 == 0) rs[row] = 1.0f / s;
    }
  }
  __syncthreads();

  // ---- S2: neff[c] = sum_i Rraw[i][c]*rs[i] -> sbin = sqrt(beta/neff) ----
  {
    const int c = tid & 127;
    const int h = tid >> 7;           // 8 slices of 16 rows
    float a = 0.0f;
    #pragma unroll 8
    for (int i = 0; i < 16; ++i) {
      const int ig = h * 16 + i;
      a = fmaf(Rn[ig * MP + c], rs[ig], a);
    }
    scr[tid] = a;
  }
  __syncthreads();
  if (tid < 128) {
    float t = 0.0f;
    #pragma unroll
    for (int m = 0; m < 8; ++m) t += scr[tid + 128 * m];
    sbin[tid] = sqrtf(betag[n] / t);
  }
  __syncthreads();

  // ---- S3a: stage Q = Rraw * diag(sbin) as f16 pairs (swizzled) ----
  {
    #pragma unroll
    for (int u = 0; u < 2; ++u) {
      const int fi8 = u * BLK + tid;      // 8-float chunk index, 0..2047
      const int r = fi8 >> 4, c8 = fi8 & 15;
      float4 lo = ldg4(Rn + r * MP + c8 * 8);
      float4 hi = ldg4(Rn + r * MP + c8 * 8 + 4);
      float4 s0 = *reinterpret_cast<const float4*>(&sbin[c8 * 8]);
      float4 s1 = *reinterpret_cast<const float4*>(&sbin[c8 * 8 + 4]);
      uint4 w;
      w.x = pkrtz(lo.x * s0.x, lo.y * s0.y);
      w.y = pkrtz(lo.z * s0.z, lo.w * s0.w);
      w.z = pkrtz(hi.x * s1.x, hi.y * s1.y);
      w.w = pkrtz(hi.z * s1.z, hi.w * s1.w);
      q16[qidx16(r, c8)] = w;
    }
  }
  __syncthreads();

  // ---- S3b: 8-wave f16 GEMM (R12-proven tiling); waves 8-15 idle ----
  if (tid < 512) {
    const int wv = tid >> 6;
    const int g4 = (tid >> 4) & 3;
    const int k4 = tid & 15;
    const int rb = wv * 16 + g4 * 4;
    const int cb = k4 * 8;
    float acc[4][8];
    #pragma unroll
    for (int r = 0; r < 4; ++r)
      #pragma unroll
      for (int c = 0; c < 8; ++c) acc[r][c] = 0.0f;
    #pragma unroll 4
    for (int ch = 0; ch < 16; ++ch) {
      uint4 qa[4], qb[8];
      #pragma unroll
      for (int r = 0; r < 4; ++r) qa[r] = q16[qidx16(rb + r, ch)];
      #pragma unroll
      for (int c = 0; c < 8; ++c) qb[c] = q16[qidx16(cb + c, ch)];
      #pragma unroll
      for (int r = 0; r < 4; ++r) {
        #pragma unroll
        for (int c = 0; c < 8; ++c) {
          float a = acc[r][c];
          a = dot2(qa[r].x, qb[c].x, a);
          a = dot2(qa[r].y, qb[c].y, a);
          a = dot2(qa[r].z, qb[c].z, a);
          a = dot2(qa[r].w, qb[c].w, a);
          acc[r][c] = a;
        }
      }
    }
    // scale G = diag(rs) Q Q^T diag(rs); pack f16 pairs; write gh
    float rsc[8];
    #pragma unroll
    for (int c = 0; c < 8; ++c) rsc[c] = rs[cb + c];
    #pragma unroll
    for (int r = 0; r < 4; ++r) {
      const float rr = rs[rb + r];
      uint4 w;
      w.x = pkrtz(acc[r][0] * rr * rsc[0], acc[r][1] * rr * rsc[1]);
      w.y = pkrtz(acc[r][2] * rr * rsc[2], acc[r][3] * rr * rsc[3]);
      w.z = pkrtz(acc[r][4] * rr * rsc[4], acc[r][5] * rr * rsc[5]);
      w.w = pkrtz(acc[r][6] * rr * rsc[6], acc[r][7] * rr * rsc[7]);
      gh[(rb + r) * 16 + k4] = w;
    }
  }
  __syncthreads();

  // ---- loop tiling: 16 waves; lane owns rows {rA, rA+1} x cols [8k..8k+8) ----
  const int w16 = tid >> 6;          // wave 0..15
  const int g = (tid >> 4) & 3;      // 16-lane DPP row
  const int k = tid & 15;
  const int rA = w16 * 8 + g * 2;    // even row; rB = rA+1

  const uint4 gva = gh[rA * 16 + k];        // G row rA, cols 8k..8k+8
  const uint4 gvb = gh[(rA + 1) * 16 + k];  // G row rA+1

  const float* Tn = Tg + n * 9;
  const float T00 = Tn[0], T01 = Tn[1], T02 = Tn[2];
  const float T10 = Tn[3], T11 = Tn[4], T12 = Tn[5];
  const float T20 = Tn[6], T21 = Tn[7], T22 = Tn[8];

  const float* rp0 = rho0g + ((size_t)n * MP + rA) * 3;
  float a0 = rp0[0], a1 = rp0[1], a2 = rp0[2];   // row rA
  float b0 = rp0[3], b1 = rp0[4], b2 = rp0[5];   // row rA+1

  if (tid < 64) {
    const float* xp = rho0g + ((size_t)n * MP + 2 * tid) * 3;
    xh[0][tid] = pkrtz(xp[0], xp[3]);
  }
  __syncthreads();

  const int xslot = w16 * 4 + g;     // = rA>>1, unique per 16-lane group
  float4* outp = reinterpret_cast<float4*>(outg) + (size_t)n * TSTEPS * MP + rA;

  for (int s = 0; s < TSTEPS; ++s) {
    // chain head: ONE b128 x-read per lane (16 contiguous uint4: 2-way = free)
    const uint4 xv = reinterpret_cast<const uint4*>(&xh[s & 1][0])[k];

    // off-chain: emit pre-update state (fire-and-forget VMEM)
    const float SA = 1.0f - ((a0 + a1) + a2);
    const float SB = 1.0f - ((b0 + b1) + b2);
    if (k == 0) outp[0] = make_float4(SA, a0, a1, a2);
    if (k == 1) outp[1] = make_float4(SB, b0, b1, b2);
    outp += MP;

    // 2x8 tile matvec via dot2
    float pA = dot2(gva.x, xv.x, 0.0f);
    pA = dot2(gva.y, xv.y, pA);
    pA = dot2(gva.z, xv.z, pA);
    pA = dot2(gva.w, xv.w, pA);
    float pB = dot2(gvb.x, xv.x, 0.0f);
    pB = dot2(gvb.y, xv.y, pB);
    pB = dot2(gvb.z, xv.z, pB);
    pB = dot2(gvb.w, xv.w, pB);

    // 16-lane rotate-add reduce; every lane ends with both row sums
    pA = dpp_radd<0x121>(pA); pA = dpp_radd<0x122>(pA);
    pA = dpp_radd<0x124>(pA); pA = dpp_radd<0x128>(pA);
    pB = dpp_radd<0x121>(pB); pB = dpp_radd<0x122>(pB);
    pB = dpp_radd<0x124>(pB); pB = dpp_radd<0x128>(pB);

    // state update + clip (both rows in every lane; writers use lane 0)
    const float n0A = clamp01(fmaf(a0, T00, fmaf(a1, T10, fmaf(a2, T20, SA * pA))));
    const float n0B = clamp01(fmaf(b0, T00, fmaf(b1, T10, fmaf(b2, T20, SB * pB))));
    if (k == 0) xh[(s & 1) ^ 1][xslot] = pkrtz(n0A, n0B);
    const float n1A = clamp01(fmaf(a0, T01, fmaf(a1, T11, a2 * T21)));
    const float n2A = clamp01(fmaf(a0, T02, fmaf(a1, T12, a2 * T22)));
    const float n1B = clamp01(fmaf(b0, T01, fmaf(b1, T11, b2 * T21)));
    const float n2B = clamp01(fmaf(b0, T02, fmaf(b1, T12, b2 * T22)));
    a0 = n0A; a1 = n1A; a2 = n2A;
    b0 = n0B; b1 = n1B; b2 = n2B;

    // LDS-only barrier: x write visible; global stores stay in flight
    step_barrier();
  }
}

} // namespace

extern "C" void kernel_launch(void* const* d_in, const int* in_sizes, int n_in,
                              void* d_out, int out_size, void* d_ws, size_t ws_size,
                              hipStream_t stream)
{
  const float* Rg    = (const float*)d_in[0];
  const float* Tg    = (const float*)d_in[1];
  const float* rho0g = (const float*)d_in[2];
  const float* betag = (const float*)d_in[3];
  float* outg = (float*)d_out;
  sir_meta_kernel<<<NS, BLK, 0, stream>>>(Rg, Tg, rho0g, betag, outg);
}

// Round 14
// 74.075 us; speedup vs baseline: 1.4770x; 1.4770x over previous
//
#include <hip/hip_runtime.h>

namespace {

constexpr int NS = 256;      // samples
constexpr int MP = 128;      // patches
constexpr int TSTEPS = 200;  // timesteps
constexpr int BLK = 512;     // 8 waves -> 2 waves/SIMD (proven optimum)

typedef _Float16 half8 __attribute__((ext_vector_type(8)));
typedef float f32x4 __attribute__((ext_vector_type(4)));

__device__ __forceinline__ float4 ldg4(const float* p) {
  return *reinterpret_cast<const float4*>(p);
}
__device__ __forceinline__ float clamp01(float v) {
  return fminf(fmaxf(v, 0.0f), 1.0f);
}
// LDS-visibility barrier that does NOT drain vmcnt (stores stay in flight).
__device__ __forceinline__ void step_barrier() {
  asm volatile("s_waitcnt lgkmcnt(0)" ::: "memory");
  __builtin_amdgcn_s_barrier();
  asm volatile("" ::: "memory");
}
// f32 += dot(f16x2, f16x2)
__device__ __forceinline__ float dot2(unsigned a, unsigned b, float c) {
  float d;
  asm("v_dot2_f32_f16 %0, %1, %2, %3" : "=v"(d) : "v"(a), "v"(b), "v"(c));
  return d;
}
// pack two f32 -> f16x2 (RTZ)
__device__ __forceinline__ unsigned pkrtz(float a, float b) {
  typedef __fp16 h2v __attribute__((ext_vector_type(2)));
  h2v r = __builtin_amdgcn_cvt_pkrtz(a, b);
  return __builtin_bit_cast(unsigned, r);
}
// fetch value from lane^1 (quad_perm [1,0,3,2])
__device__ __forceinline__ float dpp_xor1(float x) {
  int yi = __builtin_amdgcn_update_dpp(0, __float_as_int(x), 0xB1, 0xF, 0xF, true);
  return __int_as_float(yi);
}
// Swizzled uint4 (8 f16) index into f16 Q: 16 quads/row, XOR row-octet
__device__ __forceinline__ int qidx16(int row, int ch) {
  return (row << 4) + (ch ^ ((row >> 3) & 7));
}
__device__ __forceinline__ half8 h8(uint4 v) {
  return __builtin_bit_cast(half8, v);
}

__global__ __launch_bounds__(BLK, 2)
void sir_meta_kernel(const float* __restrict__ Rg,
                     const float* __restrict__ Tg,
                     const float* __restrict__ rho0g,
                     const float* __restrict__ betag,
                     float* __restrict__ outg)
{
  __shared__ __align__(16) float rs[MP];          // 1/rowsum (f32 exact)
  __shared__ __align__(16) float sbin[MP];        // sqrt(beta/neff) (f32 exact)
  __shared__ __align__(16) float scr[BLK];
  __shared__ __align__(16) unsigned xh[2][64];    // x as f16 pairs, dbuffered
  __shared__ __align__(16) uint4 q16[MP * 16];    // Q in f16 pairs (32KB)
  __shared__ __align__(16) uint4 gh[MP * 16];     // G in f16 pairs (8KB)

  const int tid = threadIdx.x;
  const int n = blockIdx.x;
  const float* __restrict__ Rn = Rg + (size_t)n * MP * MP;

  // ---- S1: row sums -> rs = 1/rowsum ----
  {
    const int wave = tid >> 6;
    const int lane = tid & 63;
    const int half = lane >> 5;
    const int l32 = lane & 31;
    for (int it = 0; it < 8; ++it) {
      const int row = wave * 16 + it * 2 + half;
      float4 v = ldg4(Rn + row * MP + l32 * 4);
      float s = (v.x + v.y) + (v.z + v.w);
      s += __shfl_xor(s, 1);
      s += __shfl_xor(s, 2);
      s += __shfl_xor(s, 4);
      s += __shfl_xor(s, 8);
      s += __shfl_xor(s, 16);
      if (l32 == 0) rs[row] = 1.0f / s;
    }
  }
  __syncthreads();

  // ---- S2: neff[c] = sum_i Rraw[i][c]*rs[i] -> sbin = sqrt(beta/neff) ----
  {
    const int c = tid & 127;
    const int h = tid >> 7;
    float a = 0.0f;
    #pragma unroll 8
    for (int i = 0; i < 32; ++i) {
      const int ig = h * 32 + i;
      a = fmaf(Rn[ig * MP + c], rs[ig], a);
    }
    scr[tid] = a;
  }
  __syncthreads();
  if (tid < 128)
    sbin[tid] = sqrtf(betag[n] /
        (((scr[tid] + scr[tid + 128]) + (scr[tid + 256] + scr[tid + 384]))));
  __syncthreads();

  // ---- S3a: stage Q = Rraw * diag(sbin) as f16 pairs (swizzled) ----
  {
    #pragma unroll
    for (int u = 0; u < 4; ++u) {
      const int fi8 = u * BLK + tid;
      const int r = fi8 >> 4, c8 = fi8 & 15;
      float4 lo = ldg4(Rn + r * MP + c8 * 8);
      float4 hi = ldg4(Rn + r * MP + c8 * 8 + 4);
      float4 s0 = *reinterpret_cast<const float4*>(&sbin[c8 * 8]);
      float4 s1 = *reinterpret_cast<const float4*>(&sbin[c8 * 8 + 4]);
      uint4 w;
      w.x = pkrtz(lo.x * s0.x, lo.y * s0.y);
      w.y = pkrtz(lo.z * s0.z, lo.w * s0.w);
      w.z = pkrtz(hi.x * s1.x, hi.y * s1.y);
      w.w = pkrtz(hi.z * s1.z, hi.w * s1.w);
      q16[qidx16(r, c8)] = w;
    }
  }
  __syncthreads();

  // ---- S3b: 8-wave f16 dot2 GEMM -> gh (G = diag(rs) Q Q^T diag(rs)) ----
  {
    const int wv = tid >> 6;
    const int g4 = (tid >> 4) & 3;
    const int k4 = tid & 15;
    const int rb = wv * 16 + g4 * 4;
    const int cb = k4 * 8;
    float acc[4][8];
    #pragma unroll
    for (int r = 0; r < 4; ++r)
      #pragma unroll
      for (int c = 0; c < 8; ++c) acc[r][c] = 0.0f;
    #pragma unroll 4
    for (int ch = 0; ch < 16; ++ch) {
      uint4 qa[4], qb[8];
      #pragma unroll
      for (int r = 0; r < 4; ++r) qa[r] = q16[qidx16(rb + r, ch)];
      #pragma unroll
      for (int c = 0; c < 8; ++c) qb[c] = q16[qidx16(cb + c, ch)];
      #pragma unroll
      for (int r = 0; r < 4; ++r) {
        #pragma unroll
        for (int c = 0; c < 8; ++c) {
          float a = acc[r][c];
          a = dot2(qa[r].x, qb[c].x, a);
          a = dot2(qa[r].y, qb[c].y, a);
          a = dot2(qa[r].z, qb[c].z, a);
          a = dot2(qa[r].w, qb[c].w, a);
          acc[r][c] = a;
        }
      }
    }
    float rsc[8];
    #pragma unroll
    for (int c = 0; c < 8; ++c) rsc[c] = rs[cb + c];
    #pragma unroll
    for (int r = 0; r < 4; ++r) {
      const float rr = rs[rb + r];
      uint4 w;
      w.x = pkrtz(acc[r][0] * rr * rsc[0], acc[r][1] * rr * rsc[1]);
      w.y = pkrtz(acc[r][2] * rr * rsc[2], acc[r][3] * rr * rsc[3]);
      w.z = pkrtz(acc[r][4] * rr * rsc[4], acc[r][5] * rr * rsc[5]);
      w.w = pkrtz(acc[r][6] * rr * rsc[6], acc[r][7] * rr * rsc[7]);
      gh[(rb + r) * 16 + k4] = w;
    }
  }
  __syncthreads();

  // ---- loop mapping: wave w owns G rows [16w..16w+16). MFMA fragments:
  // A (G tile): lane holds A[row=col][k=32c+8kg+j] -> gh[(16w+col)*16 + 4c+kg]
  // B (x, replicated in all 16 columns): lane reads xq4[4c+kg] (broadcast)
  // D (m89-verified): lane holds y[4kg+reg] for reg=0..3, any col.
  const int w = tid >> 6;
  const int l = tid & 63;
  const int col = l & 15;
  const int kg = l >> 4;
  const int jrow = 16 * w + 4 * kg + col;   // this lane's state row (col<4)
  const bool writer = (col < 4);

  uint4 af0 = gh[(16 * w + col) * 16 + 0 + kg];
  uint4 af1 = gh[(16 * w + col) * 16 + 4 + kg];
  uint4 af2 = gh[(16 * w + col) * 16 + 8 + kg];
  uint4 af3 = gh[(16 * w + col) * 16 + 12 + kg];

  const float* Tn = Tg + n * 9;
  const float T00 = Tn[0], T01 = Tn[1], T02 = Tn[2];
  const float T10 = Tn[3], T11 = Tn[4], T12 = Tn[5];
  const float T20 = Tn[6], T21 = Tn[7], T22 = Tn[8];

  float r0 = 0.f, r1 = 0.f, r2 = 0.f;
  if (writer) {
    const float* rp = rho0g + ((size_t)n * MP + jrow) * 3;
    r0 = rp[0]; r1 = rp[1]; r2 = rp[2];
  }
  if (tid < 64) {
    const float* xp = rho0g + ((size_t)n * MP + 2 * tid) * 3;
    xh[0][tid] = pkrtz(xp[0], xp[3]);
  }
  __syncthreads();

  float4* outp = reinterpret_cast<float4*>(outg) + (size_t)n * TSTEPS * MP + jrow;
  const bool xwriter = writer && ((col & 1) == 0);
  const int xslot = jrow >> 1;              // valid when col even

  for (int s = 0; s < TSTEPS; ++s) {
    // chain head: 4 broadcast uint4 x-reads (4 distinct addrs/wave)
    const uint4* xq4 = reinterpret_cast<const uint4*>(&xh[s & 1][0]);
    const uint4 b0 = xq4[kg];
    const uint4 b1 = xq4[4 + kg];
    const uint4 b2 = xq4[8 + kg];
    const uint4 b3 = xq4[12 + kg];

    // off-chain: emit pre-update state (coalesced 16-lane store per wave)
    const float S = 1.0f - ((r0 + r1) + r2);
    if (writer) *outp = make_float4(S, r0, r1, r2);
    outp += MP;

    // two 2-deep MFMA chains (K = 128 in 32-chunks), summed at select
    f32x4 accA = {0.f, 0.f, 0.f, 0.f};
    f32x4 accB = {0.f, 0.f, 0.f, 0.f};
    accA = __builtin_amdgcn_mfma_f32_16x16x32_f16(h8(af0), h8(b0), accA, 0, 0, 0);
    accB = __builtin_amdgcn_mfma_f32_16x16x32_f16(h8(af1), h8(b1), accB, 0, 0, 0);
    accA = __builtin_amdgcn_mfma_f32_16x16x32_f16(h8(af2), h8(b2), accA, 0, 0, 0);
    accB = __builtin_amdgcn_mfma_f32_16x16x32_f16(h8(af3), h8(b3), accB, 0, 0, 0);

    // static select of this lane's row-sum (reg index = col, cndmask tree)
    const float tA0 = (col & 1) ? accA[1] : accA[0];
    const float tA1 = (col & 1) ? accA[3] : accA[2];
    const float tB0 = (col & 1) ? accB[1] : accB[0];
    const float tB1 = (col & 1) ? accB[3] : accB[2];
    const float y = ((col & 2) ? tA1 : tA0) + ((col & 2) ? tB1 : tB0);

    // state update + clip
    const float ni = S * y;
    const float n0 = clamp01(fmaf(r0, T00, fmaf(r1, T10, fmaf(r2, T20, ni))));
    const float n1 = clamp01(fmaf(r0, T01, fmaf(r1, T11, r2 * T21)));
    const float n2 = clamp01(fmaf(r0, T02, fmaf(r1, T12, r2 * T22)));

    // pack adjacent rows' n0 (col pairs 0-1, 2-3 via quad_perm xor1)
    const float nb = dpp_xor1(n0);
    if (xwriter) xh[(s & 1) ^ 1][xslot] = pkrtz(n0, nb);

    r0 = n0; r1 = n1; r2 = n2;

    // LDS-only barrier: x write visible; global stores stay in flight
    step_barrier();
  }
}

} // namespace

extern "C" void kernel_launch(void* const* d_in, const int* in_sizes, int n_in,
                              void* d_out, int out_size, void* d_ws, size_t ws_size,
                              hipStream_t stream)
{
  const float* Rg    = (const float*)d_in[0];
  const float* Tg    = (const float*)d_in[1];
  const float* rho0g = (const float*)d_in[2];
  const float* betag = (const float*)d_in[3];
  float* outg = (float*)d_out;
  sir_meta_kernel<<<NS, BLK, 0, stream>>>(Rg, Tg, rho0g, betag, outg);
}